// Round 10
// baseline (264.399 us; speedup 1.0000x reference)
//
#include <hip/hip_runtime.h>
#include <math.h>

// FastRadonTransform via LDS-staged rotated-tile sampling, v8.
// fx = A + w*cos + h*sin ; fy = Bc - w*sin + h*cos (exact, H==W, align_corners).
// Base = v6 (183 us): 48row x 64col window, stride 68, XOR swizzle, adaptive
// lane mapping. NEW: channels (0,1) stored as an interleaved float2 plane ->
// each bilinear corner fetches 2 channels with ONE ds_read_b64; channel 2 in a
// scalar plane. 8 LDS reads/sample instead of 12 (LDS pipe is ISSUE-limited:
// ~5.8cyc/instr vs 1 data-clk). v7's additive-only layout resonated at
// theta~91deg (16-way band -> stragglers); XOR+additive has no such band.

constexpr int B = 2, C = 3, H = 384, W = 384, K = 180;
constexpr int TILE = 32;
constexpr int NTW  = W / TILE;      // 12
constexpr int NTH  = H / TILE;      // 12
constexpr int ROWS = 48;
constexpr int STR  = 68;            // pixel stride (68 mod 32 = 4: additive drift)
constexpr int PLN  = ROWS * STR;    // 3264 slots per plane

struct Cat { int stage; int xal; int ym; };

__device__ __forceinline__ Cat tile_cat(float A, float Bc, float sth, float cth,
                                        int h0, int tw) {
    const float w0f = (float)(tw * TILE), w1f = w0f + (TILE - 1);
    const float h0f = (float)h0,          h1f = h0f + (TILE - 1);
    const float minfx = A  + fminf(w0f * cth, w1f * cth) + fminf(h0f * sth, h1f * sth);
    const float minfy = Bc + fminf(-w0f * sth, -w1f * sth) + fminf(h0f * cth, h1f * cth);
    Cat c;
    const int xm = (int)floorf(minfx) - 1;
    c.ym  = (int)floorf(minfy) - 1;
    c.xal = xm & ~3;
    const bool skip = (xm + 47 < 0) | (xm > W - 1) | (c.ym + 47 < 0) | (c.ym > H - 1);
    c.stage = skip ? 0 : 1;
    return c;
}

// Staging: u = tid + 256j (j<3), r = u>>4 in [0,48), g = u&15 in [0,16) (dense).
// Window: rows ym..ym+47, pixel cols xal..xal+63 (xal 4-aligned).
__device__ __forceinline__ void issue_loads(const float* __restrict__ img,
                                            int tid, int xal, int ym,
                                            float4 (&pf)[C][3]) {
    #pragma unroll
    for (int c = 0; c < C; ++c) {
        const float* __restrict__ plane = img + c * (H * W);
        #pragma unroll
        for (int j = 0; j < 3; ++j) {
            const int u = tid + 256 * j;
            const int r = u >> 4;
            const int g = u & 15;
            const int gy = min(max(ym + r, 0), H - 1);
            const int gx = min(max(xal + 4 * g, 0), W - 4);  // stays 4-aligned
            pf[c][j] = *reinterpret_cast<const float4*>(plane + gy * W + gx);
        }
    }
}

__device__ __forceinline__ void write_stage(const float* __restrict__ img,
                                            float2* __restrict__ smAB,
                                            float* __restrict__ smC,
                                            int tid, int xal, int ym,
                                            const float4 (&pf)[C][3]) {
    const bool interior = (ym >= 0) & (ym <= H - ROWS) &
                          (xal >= 0) & (xal <= W - 64);
    #pragma unroll
    for (int j = 0; j < 3; ++j) {
        const int u = tid + 256 * j;
        const int r = u >> 4;
        const int g = u & 15;
        const int px = 4 * g;                       // pixel col of quad start
        const int v2 = (r & 7) << 1;                // AB swizzle (pair units, 16B)
        const int vc = (r & 7) << 2;                // C  swizzle (16B gran)
        const float4 q0 = pf[0][j];
        const float4 q1 = pf[1][j];
        const float4 q2 = pf[2][j];
        if (interior) {
            // AB: two b128 writes (2 float2 pixels each); swizzle keeps pairs
            // contiguous (v2 bit0 = 0, px even)
            *reinterpret_cast<float4*>(smAB + r * STR + ( px      ^ v2)) =
                make_float4(q0.x, q1.x, q0.y, q1.y);
            *reinterpret_cast<float4*>(smAB + r * STR + ((px + 2) ^ v2)) =
                make_float4(q0.z, q1.z, q0.w, q1.w);
            // C: one b128 (vc, px both multiples of 4)
            *reinterpret_cast<float4*>(smC + r * STR + (px ^ vc)) = q2;
        } else {
            const int gy = ym + r;
            const bool rowok = ((unsigned)gy < (unsigned)H);
            const int gyc = min(max(gy, 0), H - 1);
            const float* __restrict__ p0 = img + gyc * W;
            const float* __restrict__ p1 = p0 + H * W;
            const float* __restrict__ p2 = p1 + H * W;
            #pragma unroll
            for (int e = 0; e < 4; ++e) {
                const int gxe = xal + px + e;
                const bool ok = rowok && ((unsigned)gxe < (unsigned)W);
                const int gxc = min(max(gxe, 0), W - 1);
                const float t0 = ok ? p0[gxc] : 0.0f;
                const float t1 = ok ? p1[gxc] : 0.0f;
                const float t2 = ok ? p2[gxc] : 0.0f;
                smAB[r * STR + ((px + e) ^ v2)] = make_float2(t0, t1);
                smC [r * STR + ((px + e) ^ vc)] = t2;
            }
        }
    }
}

__global__ __launch_bounds__(256) void radon_tile(
    const float* __restrict__ x,       // (B,C,H,W)
    const float* __restrict__ angles,  // (B,K)
    float* __restrict__ out)           // (B,C,H,K)
{
    __shared__ __align__(16) float2 smAB[PLN];    // 26112 B
    __shared__ __align__(16) float  smC [PLN];    // 13056 B -> 39.2 KB total

    const int bid = blockIdx.x;
    const int th  = bid % NTH;
    const int bk  = bid / NTH;
    const int k   = bk % K;
    const int b   = bk / K;

    const int tid = threadIdx.x;
    const int u1  = tid & 31;          // fine lane index (32 values)
    const int u8  = tid >> 5;          // group index (8 values)

    const float theta = angles[b * K + k] * (3.14159265358979323846f / 180.0f);
    float sth, cth;
    sincosf(theta, &sth, &cth);

    const float A  = 0.5f * (W - 1) * (1.0f - cth - sth);
    const float Bc = 0.5f * (H - 1) * (1.0f + sth - cth);

    // mapping select (block-uniform): lanes walk the axis with x-step >= .707
    const bool mapB = fabsf(sth) > fabsf(cth);
    const int wofs = mapB ? u8 : u1;
    const int hofs = mapB ? u1 : u8;
    const float dix = mapB ? 8.0f * cth :  8.0f * sth;
    const float diy = mapB ? -8.0f * sth : 8.0f * cth;

    const int h0 = th * TILE;
    const float hf = (float)(h0 + hofs);

    const float* __restrict__ img = x + (size_t)b * (C * H * W);

    float acc[4][C];
    #pragma unroll
    for (int i = 0; i < 4; ++i)
        #pragma unroll
        for (int c = 0; c < C; ++c) acc[i][c] = 0.0f;

    float4 pf[C][3];
    Cat cur = tile_cat(A, Bc, sth, cth, h0, 0);
    if (cur.stage) issue_loads(img, tid, cur.xal, cur.ym, pf);

    for (int tw = 0; tw < NTW; ++tw) {
        Cat nxt; nxt.stage = 0; nxt.xal = 0; nxt.ym = 0;
        if (tw + 1 < NTW) nxt = tile_cat(A, Bc, sth, cth, h0, tw + 1);

        if (cur.stage) {
            __syncthreads();                       // prior sampling done
            write_stage(img, smAB, smC, tid, cur.xal, cur.ym, pf);
        }
        if (nxt.stage) issue_loads(img, tid, nxt.xal, nxt.ym, pf);  // overlap
        if (cur.stage) {
            __syncthreads();                       // LDS tile ready
            const float wf = (float)(tw * TILE + wofs);
            float fx = fmaf(hf, sth, fmaf(wf,  cth, A)) - (float)cur.xal;
            float fy = fmaf(hf, cth, fmaf(wf, -sth, Bc)) - (float)cur.ym;
            #pragma unroll
            for (int i = 0; i < 4; ++i) {
                const float xf = floorf(fx), yf = floorf(fy);
                const int lx = (int)xf;            // [1, 50] < 64
                const int ly = (int)yf;            // [1, 46] < 48
                const float wx1 = fx - xf, wy1 = fy - yf;
                const float wx0 = 1.0f - wx1, wy0 = 1.0f - wy1;
                const float w00 = wy0 * wx0, w01 = wy0 * wx1;
                const float w10 = wy1 * wx0, w11 = wy1 * wx1;
                const int row0 = ly * STR, row1 = row0 + STR;
                const int v20 = (ly & 7) << 1, v21 = ((ly + 1) & 7) << 1;
                const int vc0 = (ly & 7) << 2, vc1 = ((ly + 1) & 7) << 2;
                // channels 0,1: four ds_read_b64
                const float2 ab00 = smAB[row0 + ( lx      ^ v20)];
                const float2 ab01 = smAB[row0 + ((lx + 1) ^ v20)];
                const float2 ab10 = smAB[row1 + ( lx      ^ v21)];
                const float2 ab11 = smAB[row1 + ((lx + 1) ^ v21)];
                // channel 2: four ds_read_b32
                const float c00 = smC[row0 + ( lx      ^ vc0)];
                const float c01 = smC[row0 + ((lx + 1) ^ vc0)];
                const float c10 = smC[row1 + ( lx      ^ vc1)];
                const float c11 = smC[row1 + ((lx + 1) ^ vc1)];
                acc[i][0] = fmaf(w00, ab00.x, fmaf(w01, ab01.x,
                            fmaf(w10, ab10.x, fmaf(w11, ab11.x, acc[i][0]))));
                acc[i][1] = fmaf(w00, ab00.y, fmaf(w01, ab01.y,
                            fmaf(w10, ab10.y, fmaf(w11, ab11.y, acc[i][1]))));
                acc[i][2] = fmaf(w00, c00, fmaf(w01, c01,
                            fmaf(w10, c10, fmaf(w11, c11, acc[i][2]))));
                fx += dix; fy += diy;
            }
        }
        cur = nxt;
    }

    if (!mapB) {
        // reduce over the 32 u1-lanes (w); xor masks <32 stay in each half
        #pragma unroll
        for (int i = 0; i < 4; ++i) {
            #pragma unroll
            for (int c = 0; c < C; ++c) {
                float s = acc[i][c];
                #pragma unroll
                for (int m = 16; m >= 1; m >>= 1) s += __shfl_xor(s, m, 64);
                if (u1 == 0) {
                    const int h = h0 + u8 + 8 * i;
                    out[((size_t)(b * C + c) * H + h) * K + k] = s;
                }
            }
        }
    } else {
        // each thread owns one h = h0+u1; sum its 4 w-chunks, then reduce
        // the 8 u8-groups via the C plane (reused as scratch; sync first).
        __syncthreads();
        #pragma unroll
        for (int c = 0; c < C; ++c) {
            const float s = (acc[0][c] + acc[1][c]) + (acc[2][c] + acc[3][c]);
            smC[(c * 8 + u8) * 32 + u1] = s;
        }
        __syncthreads();
        if (tid < C * 32) {
            const int c = tid >> 5;
            const int l = tid & 31;
            float s = 0.0f;
            #pragma unroll
            for (int g = 0; g < 8; ++g) s += smC[(c * 8 + g) * 32 + l];
            out[((size_t)(b * C + c) * H + (h0 + l)) * K + k] = s;
        }
    }
}

extern "C" void kernel_launch(void* const* d_in, const int* in_sizes, int n_in,
                              void* d_out, int out_size, void* d_ws, size_t ws_size,
                              hipStream_t stream) {
    const float* x      = (const float*)d_in[0];
    const float* angles = (const float*)d_in[1];
    float* out          = (float*)d_out;

    radon_tile<<<B * K * NTH, 256, 0, stream>>>(x, angles, out);  // 4320 blocks
}

// Round 11
// 220.362 us; speedup vs baseline: 1.1998x; 1.1998x over previous
//
#include <hip/hip_runtime.h>
#include <math.h>

// FastRadonTransform via LDS-staged rotated-tile sampling, v9.
// Base = v6 (183 us): 48-row window, XOR+additive swizzle, adaptive lane map.
// NEW: channel-interleaved rows. Row r = [ch0: 68 | ch1: 68 | ch2: 68] floats,
// row stride 204 (== 0 mod 4 -> 16B-aligned b128 staging writes; scalar f32
// slots -> full 32-bank coverage; 204 mod 32 = 12 additive drift + XOR).
// A corner's 3 channels are at base/+68/+136: constant dword deltas < 256 ->
// compiler merges into ds_read2_b32 => 8 LDS instr/sample instead of 12.
// (v7 failed on 16B alignment: stride 54 != 0 mod 4. v8 failed on even-bank
// float2 elements. Both fixed here by construction.)

constexpr int B = 2, C = 3, H = 384, W = 384, K = 180;
constexpr int TILE = 32;
constexpr int NTW  = W / TILE;      // 12
constexpr int NTH  = H / TILE;      // 12
constexpr int ROWS = 48;
constexpr int CH   = 68;            // per-channel segment (64 data + 4 swz pad)
constexpr int SROW = 3 * CH;        // 204 floats; mod 32 = 12; mod 4 = 0
constexpr int PLN  = ROWS * SROW;   // 9792 floats = 39168 B -> 4 blocks/CU

struct Cat { int stage; int xal; int ym; };

__device__ __forceinline__ Cat tile_cat(float A, float Bc, float sth, float cth,
                                        int h0, int tw) {
    const float w0f = (float)(tw * TILE), w1f = w0f + (TILE - 1);
    const float h0f = (float)h0,          h1f = h0f + (TILE - 1);
    const float minfx = A  + fminf(w0f * cth, w1f * cth) + fminf(h0f * sth, h1f * sth);
    const float minfy = Bc + fminf(-w0f * sth, -w1f * sth) + fminf(h0f * cth, h1f * cth);
    Cat c;
    const int xm = (int)floorf(minfx) - 1;
    c.ym  = (int)floorf(minfy) - 1;
    c.xal = xm & ~3;
    const bool skip = (xm + 47 < 0) | (xm > W - 1) | (c.ym + 47 < 0) | (c.ym > H - 1);
    c.stage = skip ? 0 : 1;
    return c;
}

// Staging: u = tid + 256j (j<3), r = u>>4 in [0,48), g = u&15 in [0,16).
// Window: rows ym..ym+47, pixel cols xal..xal+63 (xal 4-aligned).
__device__ __forceinline__ void issue_loads(const float* __restrict__ img,
                                            int tid, int xal, int ym,
                                            float4 (&pf)[C][3]) {
    #pragma unroll
    for (int c = 0; c < C; ++c) {
        const float* __restrict__ plane = img + c * (H * W);
        #pragma unroll
        for (int j = 0; j < 3; ++j) {
            const int u = tid + 256 * j;
            const int r = u >> 4;
            const int g = u & 15;
            const int gy = min(max(ym + r, 0), H - 1);
            const int gx = min(max(xal + 4 * g, 0), W - 4);  // stays 4-aligned
            pf[c][j] = *reinterpret_cast<const float4*>(plane + gy * W + gx);
        }
    }
}

__device__ __forceinline__ void write_stage(const float* __restrict__ img,
                                            float* __restrict__ sm,
                                            int tid, int xal, int ym,
                                            const float4 (&pf)[C][3]) {
    const bool interior = (ym >= 0) & (ym <= H - ROWS) &
                          (xal >= 0) & (xal <= W - 64);
    #pragma unroll
    for (int c = 0; c < C; ++c) {
        const float* __restrict__ plane = img + c * (H * W);
        #pragma unroll
        for (int j = 0; j < 3; ++j) {
            const int u = tid + 256 * j;
            const int r = u >> 4;
            const int g = u & 15;
            const int px = 4 * g;                  // 0..60, multiple of 4
            const int vc = (r & 7) << 2;           // 16B-granular swizzle
            // slot: row base + channel segment + swizzled col (16B aligned)
            const int bs = r * SROW + c * CH + (px ^ vc);
            const float4 v = pf[c][j];
            if (interior) {
                *reinterpret_cast<float4*>(sm + bs) = v;
            } else {
                const int gy = ym + r;
                const int gx = xal + px;
                const bool rowok = ((unsigned)gy < (unsigned)H);
                if (rowok && gx >= 0 && gx <= W - 4) {
                    *reinterpret_cast<float4*>(sm + bs) = v;
                } else {
                    const int gyc = min(max(gy, 0), H - 1);
                    #pragma unroll
                    for (int e = 0; e < 4; ++e) {
                        const int gxe = gx + e;
                        const bool ok = rowok && ((unsigned)gxe < (unsigned)W);
                        const int gxc = min(max(gxe, 0), W - 1);
                        const float t = plane[gyc * W + gxc];
                        sm[bs + e] = ok ? t : 0.0f;   // (px+e)^vc == (px^vc)+e
                    }
                }
            }
        }
    }
}

__global__ __launch_bounds__(256) void radon_tile(
    const float* __restrict__ x,       // (B,C,H,W)
    const float* __restrict__ angles,  // (B,K)
    float* __restrict__ out)           // (B,C,H,K)
{
    __shared__ __align__(16) float sm[PLN];       // 39168 B

    const int bid = blockIdx.x;
    const int th  = bid % NTH;
    const int bk  = bid / NTH;
    const int k   = bk % K;
    const int b   = bk / K;

    const int tid = threadIdx.x;
    const int u1  = tid & 31;          // fine lane index (32 values)
    const int u8  = tid >> 5;          // group index (8 values)

    const float theta = angles[b * K + k] * (3.14159265358979323846f / 180.0f);
    float sth, cth;
    sincosf(theta, &sth, &cth);

    const float A  = 0.5f * (W - 1) * (1.0f - cth - sth);
    const float Bc = 0.5f * (H - 1) * (1.0f + sth - cth);

    // mapping select (block-uniform): lanes walk the axis with x-step >= .707
    const bool mapB = fabsf(sth) > fabsf(cth);
    const int wofs = mapB ? u8 : u1;
    const int hofs = mapB ? u1 : u8;
    const float dix = mapB ? 8.0f * cth :  8.0f * sth;
    const float diy = mapB ? -8.0f * sth : 8.0f * cth;

    const int h0 = th * TILE;
    const float hf = (float)(h0 + hofs);

    const float* __restrict__ img = x + (size_t)b * (C * H * W);

    float acc[4][C];
    #pragma unroll
    for (int i = 0; i < 4; ++i)
        #pragma unroll
        for (int c = 0; c < C; ++c) acc[i][c] = 0.0f;

    float4 pf[C][3];
    Cat cur = tile_cat(A, Bc, sth, cth, h0, 0);
    if (cur.stage) issue_loads(img, tid, cur.xal, cur.ym, pf);

    for (int tw = 0; tw < NTW; ++tw) {
        Cat nxt; nxt.stage = 0; nxt.xal = 0; nxt.ym = 0;
        if (tw + 1 < NTW) nxt = tile_cat(A, Bc, sth, cth, h0, tw + 1);

        if (cur.stage) {
            __syncthreads();                       // prior sampling done
            write_stage(img, sm, tid, cur.xal, cur.ym, pf);
        }
        if (nxt.stage) issue_loads(img, tid, nxt.xal, nxt.ym, pf);  // overlap
        if (cur.stage) {
            __syncthreads();                       // LDS tile ready
            const float wf = (float)(tw * TILE + wofs);
            float fx = fmaf(hf, sth, fmaf(wf,  cth, A)) - (float)cur.xal;
            float fy = fmaf(hf, cth, fmaf(wf, -sth, Bc)) - (float)cur.ym;
            #pragma unroll
            for (int i = 0; i < 4; ++i) {
                const float xf = floorf(fx), yf = floorf(fy);
                const int lx = (int)xf;            // [1, 52] <= 62 after XOR
                const int ly = (int)yf;            // [1, 46] < 48
                const float wx1 = fx - xf, wy1 = fy - yf;
                const float wx0 = 1.0f - wx1, wy0 = 1.0f - wy1;
                const float w00 = wy0 * wx0, w01 = wy0 * wx1;
                const float w10 = wy1 * wx0, w11 = wy1 * wx1;
                const int row0 = ly * SROW;
                const int v0 = (ly & 7) << 2;
                const int v1 = ((ly + 1) & 7) << 2;
                // 4 corner bases; channels at +0 / +68 / +136 (ds_read2 merge)
                const float* r0a = sm + row0 + ( lx      ^ v0);
                const float* r0b = sm + row0 + ((lx + 1) ^ v0);
                const float* r1a = sm + row0 + SROW + ( lx      ^ v1);
                const float* r1b = sm + row0 + SROW + ((lx + 1) ^ v1);
                const float a00 = r0a[0], b00 = r0a[CH], c00 = r0a[2 * CH];
                const float a01 = r0b[0], b01 = r0b[CH], c01 = r0b[2 * CH];
                const float a10 = r1a[0], b10 = r1a[CH], c10 = r1a[2 * CH];
                const float a11 = r1b[0], b11 = r1b[CH], c11 = r1b[2 * CH];
                acc[i][0] = fmaf(w00, a00, fmaf(w01, a01,
                            fmaf(w10, a10, fmaf(w11, a11, acc[i][0]))));
                acc[i][1] = fmaf(w00, b00, fmaf(w01, b01,
                            fmaf(w10, b10, fmaf(w11, b11, acc[i][1]))));
                acc[i][2] = fmaf(w00, c00, fmaf(w01, c01,
                            fmaf(w10, c10, fmaf(w11, c11, acc[i][2]))));
                fx += dix; fy += diy;
            }
        }
        cur = nxt;
    }

    if (!mapB) {
        // reduce over the 32 u1-lanes (w); xor masks <32 stay in each half
        #pragma unroll
        for (int i = 0; i < 4; ++i) {
            #pragma unroll
            for (int c = 0; c < C; ++c) {
                float s = acc[i][c];
                #pragma unroll
                for (int m = 16; m >= 1; m >>= 1) s += __shfl_xor(s, m, 64);
                if (u1 == 0) {
                    const int h = h0 + u8 + 8 * i;
                    out[((size_t)(b * C + c) * H + h) * K + k] = s;
                }
            }
        }
    } else {
        // each thread owns one h = h0+u1; sum its 4 w-chunks, then reduce
        // the 8 u8-groups through LDS (reused as scratch; sync first).
        __syncthreads();
        #pragma unroll
        for (int c = 0; c < C; ++c) {
            const float s = (acc[0][c] + acc[1][c]) + (acc[2][c] + acc[3][c]);
            sm[(c * 8 + u8) * 32 + u1] = s;
        }
        __syncthreads();
        if (tid < C * 32) {
            const int c = tid >> 5;
            const int l = tid & 31;
            float s = 0.0f;
            #pragma unroll
            for (int g = 0; g < 8; ++g) s += sm[(c * 8 + g) * 32 + l];
            out[((size_t)(b * C + c) * H + (h0 + l)) * K + k] = s;
        }
    }
}

extern "C" void kernel_launch(void* const* d_in, const int* in_sizes, int n_in,
                              void* d_out, int out_size, void* d_ws, size_t ws_size,
                              hipStream_t stream) {
    const float* x      = (const float*)d_in[0];
    const float* angles = (const float*)d_in[1];
    float* out          = (float*)d_out;

    radon_tile<<<B * K * NTH, 256, 0, stream>>>(x, angles, out);  // 4320 blocks
}